// Round 18
// baseline (255.922 us; speedup 1.0000x reference)
//
#include <hip/hip_runtime.h>
#include <hip/hip_bf16.h>
#include <hip/hip_fp16.h>

// GCN regressor: 3x GCNConv(64->64, normalize=False) + mean-pool + MLP(64->32->16->1)
// Round 18 (on best=157.8us):
//  - scanB2 folded into scanB1: block k suffix-adds its bucket total into bb0[j>k]
//    (atomic int adds: exact + deterministic). bb0/sums/cnts zero-init in histA_conv.
//    One dispatch fewer; btot deleted.
//  - pool vectorized: 8 lanes/node x uint4 (16B/lane, was 2B scalar), acc[8].
//  - agg/build otherwise unchanged from round 17.

#define HID 64
#define KNBLK 256

// ---- pass A: histogram (bucket = dst>>8) + x->fp16 conv + zero-inits ----
__global__ __launch_bounds__(256) void histA_conv_kernel(const int* __restrict__ ei,
                                                         int* __restrict__ counts,
                                                         const float* __restrict__ x,
                                                         __half* __restrict__ xh,
                                                         int* __restrict__ bb0,
                                                         float* __restrict__ sums,
                                                         float* __restrict__ cnts,
                                                         int E, int K, int chunk,
                                                         int n4, int G) {
    __shared__ int hist[256];
    int t = threadIdx.x, b = blockIdx.x;
    hist[t] = 0;
    __syncthreads();
    if (b == 0) {   // zero-init for scanB1's atomic suffix-add + pool accumulators
        for (int i = t; i <= K; i += 256) bb0[i] = 0;
        for (int i = t; i < G * 64; i += 256) sums[i] = 0.f;
        if (t < G) cnts[t] = 0.f;
    }
    int s = b * chunk, e1 = min(E, s + chunk);
    for (int i = s + t; i < e1; i += 256)
        atomicAdd(&hist[ei[E + i] >> 8], 1);
    // conv interleaved (independent): grid-stride over n4 float4 groups
    for (int i = b * 256 + t; i < n4; i += 256 * KNBLK) {
        const float4 v = *reinterpret_cast<const float4*>(x + (size_t)i * 4);
        __half2 a = __float22half2_rn(make_float2(v.x, v.y));
        __half2 b2 = __float22half2_rn(make_float2(v.z, v.w));
        uint2 u;
        u.x = __builtin_bit_cast(unsigned int, a);
        u.y = __builtin_bit_cast(unsigned int, b2);
        *reinterpret_cast<uint2*>(xh + (size_t)i * 4) = u;
    }
    __syncthreads();
    if (t < K) counts[b * K + t] = hist[t];
}

// ---- scan B1: per bucket k, exclusive scan over blocks; PLUS atomic suffix-add
//      of the bucket total into bb0[j] for j>k. After this kernel:
//      bb0[j] = sum_{k<j} bucket_total[k], bb0[K] = E. (int adds: exact) ----
__global__ __launch_bounds__(256) void scanB1_kernel(int* __restrict__ counts,
                                                     int* __restrict__ bb0, int K) {
    __shared__ int sh[256];
    int k = blockIdx.x, t = threadIdx.x;
    int v = counts[t * K + k];
    sh[t] = v;
    __syncthreads();
    #pragma unroll
    for (int d = 1; d < 256; d <<= 1) {
        int add = (t >= d) ? sh[t - d] : 0;
        __syncthreads();
        sh[t] += add;
        __syncthreads();
    }
    counts[t * K + k] = sh[t] - v;          // exclusive over blocks
    int total = sh[255];
    int j = k + 1 + t;                      // K<=256 -> one element per thread
    if (j <= K) atomicAdd(&bb0[j], total);
}

// ---- pass B: scatter edges to bucket-partitioned ebuf (packed int2 records) ----
__global__ __launch_bounds__(256) void passB_kernel(const int* __restrict__ ei,
                                                    const float* __restrict__ ew,
                                                    const int* __restrict__ counts,
                                                    const int* __restrict__ bb0,
                                                    int2* __restrict__ ebuf,
                                                    int E, int K, int chunk) {
    __shared__ int lcur[256];
    int t = threadIdx.x, b = blockIdx.x;
    lcur[t] = 0;
    __syncthreads();
    int s = b * chunk, e1 = min(E, s + chunk);
    for (int i = s + t; i < e1; i += 256) {
        int src = ei[i];
        int dst = ei[E + i];
        float w = ew[i];
        int k = dst >> 8;
        int idx = atomicAdd(&lcur[k], 1);
        int slot = bb0[k] + counts[b * K + k] + idx;
        ebuf[slot] = make_int2(src | ((dst & 255) << 16), __float_as_int(w));
    }
}

// ---- pass C: per-bucket counting sort -> final CSR (int2{src,wbits}) + offs ----
__global__ __launch_bounds__(256) void passC_kernel(const int2* __restrict__ ebuf,
                                                    const int* __restrict__ bb0,
                                                    int2* __restrict__ csr,
                                                    int* __restrict__ offs,
                                                    int N, int E, int K) {
    __shared__ int ldeg[256];
    __shared__ int sh[256];
    __shared__ int lofs[256];
    int b = blockIdx.x, t = threadIdx.x;
    int gb0 = bb0[b], gb1 = bb0[b + 1];
    int cnt = gb1 - gb0;
    int base = b << 8;
    ldeg[t] = 0;
    __syncthreads();
    for (int i = t; i < cnt; i += 256)
        atomicAdd(&ldeg[(ebuf[gb0 + i].x >> 16) & 255], 1);
    __syncthreads();
    int v = ldeg[t];
    sh[t] = v;
    __syncthreads();
    #pragma unroll
    for (int d = 1; d < 256; d <<= 1) {
        int add = (t >= d) ? sh[t - d] : 0;
        __syncthreads();
        sh[t] += add;
        __syncthreads();
    }
    lofs[t] = sh[t] - v;
    int nInB = min(256, N - base);
    if (t < nInB) offs[base + t] = gb0 + lofs[t];
    if (b == K - 1 && t == 0) offs[N] = E;
    __syncthreads();
    for (int i = t; i < cnt; i += 256) {
        int2 r = ebuf[gb0 + i];
        int d = (r.x >> 16) & 255;
        int pos = atomicAdd(&lofs[d], 1);
        csr[gb0 + pos] = make_int2(r.x & 0xFFFF, r.y);
    }
}

// Fused layer: out[n][:] = relu( (sum_{e in CSR(n)} w_e * prev[src_e][:]) @ W + b )
// 8 lanes/node; lane l owns channels 8l..8l+7 (one uint4 = 16B fp16 load).
// fp32 accumulate; x4 unroll; width-8 shfl epilogue; 16B fp16 store.
__global__ __launch_bounds__(256) void agg_fused_kernel(const __half* __restrict__ prev,
                                                        const int2* __restrict__ csr,
                                                        const int* __restrict__ offs,
                                                        const float* __restrict__ W,
                                                        const float* __restrict__ bias,
                                                        __half* __restrict__ out, int N) {
    __shared__ float Wl[64 * 64];
    __shared__ float bl[64];
    for (int i = threadIdx.x; i < 64 * 64; i += 256) Wl[i] = W[i];
    if (threadIdx.x < 64) bl[threadIdx.x] = bias[threadIdx.x];
    __syncthreads();

    int g = (blockIdx.x * 256 + threadIdx.x) >> 3;   // node (8 lanes each)
    int l = threadIdx.x & 7;                         // lane: channels 8l..8l+7
    if (g >= N) return;

    int e0 = offs[g], e1 = offs[g + 1];
    float acc[8] = {0.f, 0.f, 0.f, 0.f, 0.f, 0.f, 0.f, 0.f};

    #define GLOAD(R, U)                                                              \
        const uint4 U = *reinterpret_cast<const uint4*>(prev + (size_t)(R).x * 64 + l * 8);
    #define GACC(U, WW)                                                              \
        {                                                                            \
            const float2 f0 = __half22float2(__builtin_bit_cast(__half2, (U).x));    \
            const float2 f1 = __half22float2(__builtin_bit_cast(__half2, (U).y));    \
            const float2 f2 = __half22float2(__builtin_bit_cast(__half2, (U).z));    \
            const float2 f3 = __half22float2(__builtin_bit_cast(__half2, (U).w));    \
            acc[0] = fmaf((WW), f0.x, acc[0]); acc[1] = fmaf((WW), f0.y, acc[1]);    \
            acc[2] = fmaf((WW), f1.x, acc[2]); acc[3] = fmaf((WW), f1.y, acc[3]);    \
            acc[4] = fmaf((WW), f2.x, acc[4]); acc[5] = fmaf((WW), f2.y, acc[5]);    \
            acc[6] = fmaf((WW), f3.x, acc[6]); acc[7] = fmaf((WW), f3.y, acc[7]);    \
        }

    int e = e0;
    for (; e + 4 <= e1; e += 4) {
        int2 r0 = csr[e + 0];
        int2 r1 = csr[e + 1];
        int2 r2 = csr[e + 2];
        int2 r3 = csr[e + 3];
        GLOAD(r0, ua);
        GLOAD(r1, ub);
        GLOAD(r2, uc);
        GLOAD(r3, ud);
        GACC(ua, __int_as_float(r0.y));
        GACC(ub, __int_as_float(r1.y));
        GACC(uc, __int_as_float(r2.y));
        GACC(ud, __int_as_float(r3.y));
    }
    for (; e < e1; ++e) {
        int2 r = csr[e];
        GLOAD(r, ue);
        GACC(ue, __int_as_float(r.y));
    }
    #undef GLOAD
    #undef GACC

    float o[8];
    #pragma unroll
    for (int j = 0; j < 8; ++j) o[j] = bl[l * 8 + j];
    #pragma unroll
    for (int k2 = 0; k2 < 8; ++k2) {
        float c[8];
        #pragma unroll
        for (int j = 0; j < 8; ++j) c[j] = __shfl(acc[j], k2, 8);
        #pragma unroll
        for (int j = 0; j < 8; ++j) {
            const float4 wa = *reinterpret_cast<const float4*>(Wl + (8 * k2 + j) * 64 + l * 8);
            const float4 wb = *reinterpret_cast<const float4*>(Wl + (8 * k2 + j) * 64 + l * 8 + 4);
            o[0] = fmaf(c[j], wa.x, o[0]); o[1] = fmaf(c[j], wa.y, o[1]);
            o[2] = fmaf(c[j], wa.z, o[2]); o[3] = fmaf(c[j], wa.w, o[3]);
            o[4] = fmaf(c[j], wb.x, o[4]); o[5] = fmaf(c[j], wb.y, o[5]);
            o[6] = fmaf(c[j], wb.z, o[6]); o[7] = fmaf(c[j], wb.w, o[7]);
        }
    }
    uint4 u;
    u.x = __builtin_bit_cast(unsigned int,
          __float22half2_rn(make_float2(fmaxf(o[0], 0.f), fmaxf(o[1], 0.f))));
    u.y = __builtin_bit_cast(unsigned int,
          __float22half2_rn(make_float2(fmaxf(o[2], 0.f), fmaxf(o[3], 0.f))));
    u.z = __builtin_bit_cast(unsigned int,
          __float22half2_rn(make_float2(fmaxf(o[4], 0.f), fmaxf(o[5], 0.f))));
    u.w = __builtin_bit_cast(unsigned int,
          __float22half2_rn(make_float2(fmaxf(o[6], 0.f), fmaxf(o[7], 0.f))));
    *reinterpret_cast<uint4*>(out + (size_t)g * 64 + l * 8) = u;
}

// Mean-pool stage 1 (fp16 input): vectorized run-length accumulate.
// 8 lanes/node-row: lane l loads uint4 = channels 8l..8l+7 (16B, was 2B scalar).
// 32 row-stripes per block; sorted batch -> register runs, few atomics.
__global__ __launch_bounds__(256) void pool_kernel(const __half* __restrict__ a,
                                                   const int* __restrict__ batch,
                                                   float* __restrict__ sums,
                                                   float* __restrict__ cnts, int N) {
    int l = threadIdx.x & 7;          // channel group: 8l..8l+7
    int sub = threadIdx.x >> 3;       // 0..31 row stripe
    int chunk = (N + gridDim.x - 1) / gridDim.x;
    int start = blockIdx.x * chunk;
    int end = min(N, start + chunk);
    int curg = -1;
    float acc[8] = {0.f, 0.f, 0.f, 0.f, 0.f, 0.f, 0.f, 0.f};
    float cacc = 0.f;
    for (int n = start + sub; n < end; n += 32) {
        int g = batch[n];
        if (g != curg) {
            if (curg >= 0) {
                #pragma unroll
                for (int j = 0; j < 8; ++j)
                    atomicAdd(&sums[curg * 64 + l * 8 + j], acc[j]);
                if (l == 0) atomicAdd(&cnts[curg], cacc);
            }
            curg = g;
            #pragma unroll
            for (int j = 0; j < 8; ++j) acc[j] = 0.f;
            cacc = 0.f;
        }
        const uint4 u = *reinterpret_cast<const uint4*>(a + (size_t)n * 64 + l * 8);
        const float2 f0 = __half22float2(__builtin_bit_cast(__half2, u.x));
        const float2 f1 = __half22float2(__builtin_bit_cast(__half2, u.y));
        const float2 f2 = __half22float2(__builtin_bit_cast(__half2, u.z));
        const float2 f3 = __half22float2(__builtin_bit_cast(__half2, u.w));
        acc[0] += f0.x; acc[1] += f0.y;
        acc[2] += f1.x; acc[3] += f1.y;
        acc[4] += f2.x; acc[5] += f2.y;
        acc[6] += f3.x; acc[7] += f3.y;
        cacc += 1.f;
    }
    if (curg >= 0) {
        #pragma unroll
        for (int j = 0; j < 8; ++j)
            atomicAdd(&sums[curg * 64 + l * 8 + j], acc[j]);
        if (l == 0) atomicAdd(&cnts[curg], cacc);
    }
}

// MLP head: pooled[G][64] -> relu(@lw1 64x32) -> relu(@lw2 32x16) -> @lw3 16x1
__global__ __launch_bounds__(256) void head_kernel(const float* __restrict__ sums,
                                                   const float* __restrict__ cnts,
                                                   const float* __restrict__ lw1,
                                                   const float* __restrict__ lb1,
                                                   const float* __restrict__ lw2,
                                                   const float* __restrict__ lb2,
                                                   const float* __restrict__ lw3,
                                                   const float* __restrict__ lb3,
                                                   float* __restrict__ out, int G) {
    __shared__ float pooled[64 * 64];
    __shared__ float z1[64 * 32];
    __shared__ float z2[64 * 16];
    int tid = threadIdx.x;
    for (int i = tid; i < G * 64; i += 256) {
        int g = i >> 6;
        float cn = cnts[g];
        cn = (cn < 1.f) ? 1.f : cn;
        pooled[i] = sums[i] / cn;
    }
    __syncthreads();
    for (int i = tid; i < G * 32; i += 256) {
        int g = i >> 5, j = i & 31;
        float acc = lb1[j];
        #pragma unroll
        for (int k = 0; k < 64; ++k) acc = fmaf(pooled[g * 64 + k], lw1[k * 32 + j], acc);
        z1[i] = fmaxf(acc, 0.f);
    }
    __syncthreads();
    for (int i = tid; i < G * 16; i += 256) {
        int g = i >> 4, j = i & 15;
        float acc = lb2[j];
        #pragma unroll
        for (int k = 0; k < 32; ++k) acc = fmaf(z1[g * 32 + k], lw2[k * 16 + j], acc);
        z2[i] = fmaxf(acc, 0.f);
    }
    __syncthreads();
    if (tid < G) {
        float acc = lb3[0];
        #pragma unroll
        for (int k = 0; k < 16; ++k) acc = fmaf(z2[tid * 16 + k], lw3[k], acc);
        out[tid] = acc;
    }
}

static inline size_t align256(size_t x) { return (x + 255) & ~(size_t)255; }

extern "C" void kernel_launch(void* const* d_in, const int* in_sizes, int n_in,
                              void* d_out, int out_size, void* d_ws, size_t ws_size,
                              hipStream_t stream) {
    const float* x     = (const float*)d_in[0];
    const int*   ei    = (const int*)d_in[1];     // (2,E): [0..E)=src, [E..2E)=dst
    const float* ew    = (const float*)d_in[2];
    const int*   batch = (const int*)d_in[3];
    const float* W1 = (const float*)d_in[4];
    const float* b1 = (const float*)d_in[5];
    const float* W2 = (const float*)d_in[6];
    const float* b2 = (const float*)d_in[7];
    const float* W3 = (const float*)d_in[8];
    const float* b3 = (const float*)d_in[9];
    const float* lw1 = (const float*)d_in[10];
    const float* lb1 = (const float*)d_in[11];
    const float* lw2 = (const float*)d_in[12];
    const float* lb2 = (const float*)d_in[13];
    const float* lw3 = (const float*)d_in[14];
    const float* lb3 = (const float*)d_in[15];
    float* out = (float*)d_out;

    const int N = in_sizes[0] / 64;
    const int E = in_sizes[2];
    const int G = out_size;
    const int K = (N + 255) >> 8;
    const int chunk = (E + KNBLK - 1) / KNBLK;

    // Workspace carve.
    char* w = (char*)d_ws;
    size_t off = 0;
    auto carve = [&](size_t bytes) -> void* {
        void* p = w + off;
        off = align256(off + bytes);
        return p;
    };
    __half* xh    = (__half*)carve((size_t)N * 64 * 2);
    __half* hA    = (__half*)carve((size_t)N * 64 * 2);
    __half* hB    = (__half*)carve((size_t)N * 64 * 2);
    int2*  csr    = (int2*)carve((size_t)E * 8);
    int2*  ebuf   = (int2*)carve((size_t)E * 8);
    int*   counts = (int*)carve((size_t)KNBLK * K * 4);
    int*   bb0    = (int*)carve((size_t)(K + 1) * 4);
    int*   offs   = (int*)carve((size_t)(N + 1) * 4);
    float* sums   = (float*)carve((size_t)G * 64 * 4);
    float* cnts   = (float*)carve((size_t)G * 4);
    (void)ws_size; (void)n_in;

    const int n4 = N * 64 / 4;

    // ---- CSR build (hist + conv + zero-inits fused; scanB1 includes bb0 scan) ----
    histA_conv_kernel<<<KNBLK, 256, 0, stream>>>(ei, counts, x, xh, bb0, sums, cnts,
                                                 E, K, chunk, n4, G);
    scanB1_kernel<<<K,     256, 0, stream>>>(counts, bb0, K);
    passB_kernel <<<KNBLK, 256, 0, stream>>>(ei, ew, counts, bb0, ebuf, E, K, chunk);
    passC_kernel <<<K,     256, 0, stream>>>(ebuf, bb0, csr, offs, N, E, K);

    const int AGG_BLOCKS = (int)(((size_t)N * 8 + 255) / 256);

    // ---- 3 fused layers: agg (fp16 gather, fp32 accum) -> @W + b -> relu ----
    agg_fused_kernel<<<AGG_BLOCKS, 256, 0, stream>>>(xh, csr, offs, W1, b1, hA, N);
    agg_fused_kernel<<<AGG_BLOCKS, 256, 0, stream>>>(hA, csr, offs, W2, b2, hB, N);
    agg_fused_kernel<<<AGG_BLOCKS, 256, 0, stream>>>(hB, csr, offs, W3, b3, hA, N);

    // ---- pool + head ----
    pool_kernel<<<512, 256, 0, stream>>>(hA, batch, sums, cnts, N);
    head_kernel<<<1, 256, 0, stream>>>(sums, cnts, lw1, lb1, lw2, lb2, lw3, lb3, out, G);
}

// Round 19
// 158.278 us; speedup vs baseline: 1.6169x; 1.6169x over previous
//
#include <hip/hip_runtime.h>
#include <hip/hip_bf16.h>
#include <hip/hip_fp16.h>

// GCN regressor: 3x GCNConv(64->64, normalize=False) + mean-pool + MLP(64->32->16->1)
// Round 19: REVERT round-18 pool vectorization (134us vs ~8: 8x more atomics on a
// 16KB region, run-length amortization destroyed). Pool back to round-17 scalar
// form (1024 blocks, 4 sub-stripes, 1 atomic/run/lane).
// KEPT from round 18: scanB2 folded into scanB1 (atomic suffix-add, exact int),
// bb0/sums/cnts zero-init in histA_conv, conv fused into histA.

#define HID 64
#define KNBLK 256

// ---- pass A: histogram (bucket = dst>>8) + x->fp16 conv + zero-inits ----
__global__ __launch_bounds__(256) void histA_conv_kernel(const int* __restrict__ ei,
                                                         int* __restrict__ counts,
                                                         const float* __restrict__ x,
                                                         __half* __restrict__ xh,
                                                         int* __restrict__ bb0,
                                                         float* __restrict__ sums,
                                                         float* __restrict__ cnts,
                                                         int E, int K, int chunk,
                                                         int n4, int G) {
    __shared__ int hist[256];
    int t = threadIdx.x, b = blockIdx.x;
    hist[t] = 0;
    __syncthreads();
    if (b == 0) {   // zero-init for scanB1's atomic suffix-add + pool accumulators
        for (int i = t; i <= K; i += 256) bb0[i] = 0;
        for (int i = t; i < G * 64; i += 256) sums[i] = 0.f;
        if (t < G) cnts[t] = 0.f;
    }
    int s = b * chunk, e1 = min(E, s + chunk);
    for (int i = s + t; i < e1; i += 256)
        atomicAdd(&hist[ei[E + i] >> 8], 1);
    // conv interleaved (independent): grid-stride over n4 float4 groups
    for (int i = b * 256 + t; i < n4; i += 256 * KNBLK) {
        const float4 v = *reinterpret_cast<const float4*>(x + (size_t)i * 4);
        __half2 a = __float22half2_rn(make_float2(v.x, v.y));
        __half2 b2 = __float22half2_rn(make_float2(v.z, v.w));
        uint2 u;
        u.x = __builtin_bit_cast(unsigned int, a);
        u.y = __builtin_bit_cast(unsigned int, b2);
        *reinterpret_cast<uint2*>(xh + (size_t)i * 4) = u;
    }
    __syncthreads();
    if (t < K) counts[b * K + t] = hist[t];
}

// ---- scan B1: per bucket k, exclusive scan over blocks; PLUS atomic suffix-add
//      of the bucket total into bb0[j] for j>k. After this kernel:
//      bb0[j] = sum_{k<j} bucket_total[k], bb0[K] = E. (int adds: exact) ----
__global__ __launch_bounds__(256) void scanB1_kernel(int* __restrict__ counts,
                                                     int* __restrict__ bb0, int K) {
    __shared__ int sh[256];
    int k = blockIdx.x, t = threadIdx.x;
    int v = counts[t * K + k];
    sh[t] = v;
    __syncthreads();
    #pragma unroll
    for (int d = 1; d < 256; d <<= 1) {
        int add = (t >= d) ? sh[t - d] : 0;
        __syncthreads();
        sh[t] += add;
        __syncthreads();
    }
    counts[t * K + k] = sh[t] - v;          // exclusive over blocks
    int total = sh[255];
    int j = k + 1 + t;                      // K<=256 -> one element per thread
    if (j <= K) atomicAdd(&bb0[j], total);
}

// ---- pass B: scatter edges to bucket-partitioned ebuf (packed int2 records) ----
__global__ __launch_bounds__(256) void passB_kernel(const int* __restrict__ ei,
                                                    const float* __restrict__ ew,
                                                    const int* __restrict__ counts,
                                                    const int* __restrict__ bb0,
                                                    int2* __restrict__ ebuf,
                                                    int E, int K, int chunk) {
    __shared__ int lcur[256];
    int t = threadIdx.x, b = blockIdx.x;
    lcur[t] = 0;
    __syncthreads();
    int s = b * chunk, e1 = min(E, s + chunk);
    for (int i = s + t; i < e1; i += 256) {
        int src = ei[i];
        int dst = ei[E + i];
        float w = ew[i];
        int k = dst >> 8;
        int idx = atomicAdd(&lcur[k], 1);
        int slot = bb0[k] + counts[b * K + k] + idx;
        ebuf[slot] = make_int2(src | ((dst & 255) << 16), __float_as_int(w));
    }
}

// ---- pass C: per-bucket counting sort -> final CSR (int2{src,wbits}) + offs ----
__global__ __launch_bounds__(256) void passC_kernel(const int2* __restrict__ ebuf,
                                                    const int* __restrict__ bb0,
                                                    int2* __restrict__ csr,
                                                    int* __restrict__ offs,
                                                    int N, int E, int K) {
    __shared__ int ldeg[256];
    __shared__ int sh[256];
    __shared__ int lofs[256];
    int b = blockIdx.x, t = threadIdx.x;
    int gb0 = bb0[b], gb1 = bb0[b + 1];
    int cnt = gb1 - gb0;
    int base = b << 8;
    ldeg[t] = 0;
    __syncthreads();
    for (int i = t; i < cnt; i += 256)
        atomicAdd(&ldeg[(ebuf[gb0 + i].x >> 16) & 255], 1);
    __syncthreads();
    int v = ldeg[t];
    sh[t] = v;
    __syncthreads();
    #pragma unroll
    for (int d = 1; d < 256; d <<= 1) {
        int add = (t >= d) ? sh[t - d] : 0;
        __syncthreads();
        sh[t] += add;
        __syncthreads();
    }
    lofs[t] = sh[t] - v;
    int nInB = min(256, N - base);
    if (t < nInB) offs[base + t] = gb0 + lofs[t];
    if (b == K - 1 && t == 0) offs[N] = E;
    __syncthreads();
    for (int i = t; i < cnt; i += 256) {
        int2 r = ebuf[gb0 + i];
        int d = (r.x >> 16) & 255;
        int pos = atomicAdd(&lofs[d], 1);
        csr[gb0 + pos] = make_int2(r.x & 0xFFFF, r.y);
    }
}

// Fused layer: out[n][:] = relu( (sum_{e in CSR(n)} w_e * prev[src_e][:]) @ W + b )
// 8 lanes/node; lane l owns channels 8l..8l+7 (one uint4 = 16B fp16 load).
// fp32 accumulate; x4 unroll; width-8 shfl epilogue; 16B fp16 store.
__global__ __launch_bounds__(256) void agg_fused_kernel(const __half* __restrict__ prev,
                                                        const int2* __restrict__ csr,
                                                        const int* __restrict__ offs,
                                                        const float* __restrict__ W,
                                                        const float* __restrict__ bias,
                                                        __half* __restrict__ out, int N) {
    __shared__ float Wl[64 * 64];
    __shared__ float bl[64];
    for (int i = threadIdx.x; i < 64 * 64; i += 256) Wl[i] = W[i];
    if (threadIdx.x < 64) bl[threadIdx.x] = bias[threadIdx.x];
    __syncthreads();

    int g = (blockIdx.x * 256 + threadIdx.x) >> 3;   // node (8 lanes each)
    int l = threadIdx.x & 7;                         // lane: channels 8l..8l+7
    if (g >= N) return;

    int e0 = offs[g], e1 = offs[g + 1];
    float acc[8] = {0.f, 0.f, 0.f, 0.f, 0.f, 0.f, 0.f, 0.f};

    #define GLOAD(R, U)                                                              \
        const uint4 U = *reinterpret_cast<const uint4*>(prev + (size_t)(R).x * 64 + l * 8);
    #define GACC(U, WW)                                                              \
        {                                                                            \
            const float2 f0 = __half22float2(__builtin_bit_cast(__half2, (U).x));    \
            const float2 f1 = __half22float2(__builtin_bit_cast(__half2, (U).y));    \
            const float2 f2 = __half22float2(__builtin_bit_cast(__half2, (U).z));    \
            const float2 f3 = __half22float2(__builtin_bit_cast(__half2, (U).w));    \
            acc[0] = fmaf((WW), f0.x, acc[0]); acc[1] = fmaf((WW), f0.y, acc[1]);    \
            acc[2] = fmaf((WW), f1.x, acc[2]); acc[3] = fmaf((WW), f1.y, acc[3]);    \
            acc[4] = fmaf((WW), f2.x, acc[4]); acc[5] = fmaf((WW), f2.y, acc[5]);    \
            acc[6] = fmaf((WW), f3.x, acc[6]); acc[7] = fmaf((WW), f3.y, acc[7]);    \
        }

    int e = e0;
    for (; e + 4 <= e1; e += 4) {
        int2 r0 = csr[e + 0];
        int2 r1 = csr[e + 1];
        int2 r2 = csr[e + 2];
        int2 r3 = csr[e + 3];
        GLOAD(r0, ua);
        GLOAD(r1, ub);
        GLOAD(r2, uc);
        GLOAD(r3, ud);
        GACC(ua, __int_as_float(r0.y));
        GACC(ub, __int_as_float(r1.y));
        GACC(uc, __int_as_float(r2.y));
        GACC(ud, __int_as_float(r3.y));
    }
    for (; e < e1; ++e) {
        int2 r = csr[e];
        GLOAD(r, ue);
        GACC(ue, __int_as_float(r.y));
    }
    #undef GLOAD
    #undef GACC

    float o[8];
    #pragma unroll
    for (int j = 0; j < 8; ++j) o[j] = bl[l * 8 + j];
    #pragma unroll
    for (int k2 = 0; k2 < 8; ++k2) {
        float c[8];
        #pragma unroll
        for (int j = 0; j < 8; ++j) c[j] = __shfl(acc[j], k2, 8);
        #pragma unroll
        for (int j = 0; j < 8; ++j) {
            const float4 wa = *reinterpret_cast<const float4*>(Wl + (8 * k2 + j) * 64 + l * 8);
            const float4 wb = *reinterpret_cast<const float4*>(Wl + (8 * k2 + j) * 64 + l * 8 + 4);
            o[0] = fmaf(c[j], wa.x, o[0]); o[1] = fmaf(c[j], wa.y, o[1]);
            o[2] = fmaf(c[j], wa.z, o[2]); o[3] = fmaf(c[j], wa.w, o[3]);
            o[4] = fmaf(c[j], wb.x, o[4]); o[5] = fmaf(c[j], wb.y, o[5]);
            o[6] = fmaf(c[j], wb.z, o[6]); o[7] = fmaf(c[j], wb.w, o[7]);
        }
    }
    uint4 u;
    u.x = __builtin_bit_cast(unsigned int,
          __float22half2_rn(make_float2(fmaxf(o[0], 0.f), fmaxf(o[1], 0.f))));
    u.y = __builtin_bit_cast(unsigned int,
          __float22half2_rn(make_float2(fmaxf(o[2], 0.f), fmaxf(o[3], 0.f))));
    u.z = __builtin_bit_cast(unsigned int,
          __float22half2_rn(make_float2(fmaxf(o[4], 0.f), fmaxf(o[5], 0.f))));
    u.w = __builtin_bit_cast(unsigned int,
          __float22half2_rn(make_float2(fmaxf(o[6], 0.f), fmaxf(o[7], 0.f))));
    *reinterpret_cast<uint4*>(out + (size_t)g * 64 + l * 8) = u;
}

// Mean-pool stage 1 (fp16 input): sorted batch -> register run-length accumulate.
// Round-17 scalar form: lane c = tid&63 owns channel c; 4 node sub-stripes;
// long runs -> ~1 atomic per run per lane.
__global__ __launch_bounds__(256) void pool_kernel(const __half* __restrict__ a,
                                                   const int* __restrict__ batch,
                                                   float* __restrict__ sums,
                                                   float* __restrict__ cnts, int N) {
    int c = threadIdx.x & 63;
    int sub = threadIdx.x >> 6;   // 0..3
    int chunk = (N + gridDim.x - 1) / gridDim.x;
    int start = blockIdx.x * chunk;
    int end = min(N, start + chunk);
    int curg = -1;
    float acc = 0.f, cacc = 0.f;
    for (int n = start + sub; n < end; n += 4) {
        int g = batch[n];
        if (g != curg) {
            if (curg >= 0) {
                atomicAdd(&sums[curg * 64 + c], acc);
                if (c == 0) atomicAdd(&cnts[curg], cacc);
            }
            curg = g; acc = 0.f; cacc = 0.f;
        }
        acc += __half2float(a[(size_t)n * 64 + c]);
        cacc += 1.f;
    }
    if (curg >= 0) {
        atomicAdd(&sums[curg * 64 + c], acc);
        if (c == 0) atomicAdd(&cnts[curg], cacc);
    }
}

// MLP head: pooled[G][64] -> relu(@lw1 64x32) -> relu(@lw2 32x16) -> @lw3 16x1
__global__ __launch_bounds__(256) void head_kernel(const float* __restrict__ sums,
                                                   const float* __restrict__ cnts,
                                                   const float* __restrict__ lw1,
                                                   const float* __restrict__ lb1,
                                                   const float* __restrict__ lw2,
                                                   const float* __restrict__ lb2,
                                                   const float* __restrict__ lw3,
                                                   const float* __restrict__ lb3,
                                                   float* __restrict__ out, int G) {
    __shared__ float pooled[64 * 64];
    __shared__ float z1[64 * 32];
    __shared__ float z2[64 * 16];
    int tid = threadIdx.x;
    for (int i = tid; i < G * 64; i += 256) {
        int g = i >> 6;
        float cn = cnts[g];
        cn = (cn < 1.f) ? 1.f : cn;
        pooled[i] = sums[i] / cn;
    }
    __syncthreads();
    for (int i = tid; i < G * 32; i += 256) {
        int g = i >> 5, j = i & 31;
        float acc = lb1[j];
        #pragma unroll
        for (int k = 0; k < 64; ++k) acc = fmaf(pooled[g * 64 + k], lw1[k * 32 + j], acc);
        z1[i] = fmaxf(acc, 0.f);
    }
    __syncthreads();
    for (int i = tid; i < G * 16; i += 256) {
        int g = i >> 4, j = i & 15;
        float acc = lb2[j];
        #pragma unroll
        for (int k = 0; k < 32; ++k) acc = fmaf(z1[g * 32 + k], lw2[k * 16 + j], acc);
        z2[i] = fmaxf(acc, 0.f);
    }
    __syncthreads();
    if (tid < G) {
        float acc = lb3[0];
        #pragma unroll
        for (int k = 0; k < 16; ++k) acc = fmaf(z2[tid * 16 + k], lw3[k], acc);
        out[tid] = acc;
    }
}

static inline size_t align256(size_t x) { return (x + 255) & ~(size_t)255; }

extern "C" void kernel_launch(void* const* d_in, const int* in_sizes, int n_in,
                              void* d_out, int out_size, void* d_ws, size_t ws_size,
                              hipStream_t stream) {
    const float* x     = (const float*)d_in[0];
    const int*   ei    = (const int*)d_in[1];     // (2,E): [0..E)=src, [E..2E)=dst
    const float* ew    = (const float*)d_in[2];
    const int*   batch = (const int*)d_in[3];
    const float* W1 = (const float*)d_in[4];
    const float* b1 = (const float*)d_in[5];
    const float* W2 = (const float*)d_in[6];
    const float* b2 = (const float*)d_in[7];
    const float* W3 = (const float*)d_in[8];
    const float* b3 = (const float*)d_in[9];
    const float* lw1 = (const float*)d_in[10];
    const float* lb1 = (const float*)d_in[11];
    const float* lw2 = (const float*)d_in[12];
    const float* lb2 = (const float*)d_in[13];
    const float* lw3 = (const float*)d_in[14];
    const float* lb3 = (const float*)d_in[15];
    float* out = (float*)d_out;

    const int N = in_sizes[0] / 64;
    const int E = in_sizes[2];
    const int G = out_size;
    const int K = (N + 255) >> 8;
    const int chunk = (E + KNBLK - 1) / KNBLK;

    // Workspace carve.
    char* w = (char*)d_ws;
    size_t off = 0;
    auto carve = [&](size_t bytes) -> void* {
        void* p = w + off;
        off = align256(off + bytes);
        return p;
    };
    __half* xh    = (__half*)carve((size_t)N * 64 * 2);
    __half* hA    = (__half*)carve((size_t)N * 64 * 2);
    __half* hB    = (__half*)carve((size_t)N * 64 * 2);
    int2*  csr    = (int2*)carve((size_t)E * 8);
    int2*  ebuf   = (int2*)carve((size_t)E * 8);
    int*   counts = (int*)carve((size_t)KNBLK * K * 4);
    int*   bb0    = (int*)carve((size_t)(K + 1) * 4);
    int*   offs   = (int*)carve((size_t)(N + 1) * 4);
    float* sums   = (float*)carve((size_t)G * 64 * 4);
    float* cnts   = (float*)carve((size_t)G * 4);
    (void)ws_size; (void)n_in;

    const int n4 = N * 64 / 4;

    // ---- CSR build (hist + conv + zero-inits fused; scanB1 includes bb0 scan) ----
    histA_conv_kernel<<<KNBLK, 256, 0, stream>>>(ei, counts, x, xh, bb0, sums, cnts,
                                                 E, K, chunk, n4, G);
    scanB1_kernel<<<K,     256, 0, stream>>>(counts, bb0, K);
    passB_kernel <<<KNBLK, 256, 0, stream>>>(ei, ew, counts, bb0, ebuf, E, K, chunk);
    passC_kernel <<<K,     256, 0, stream>>>(ebuf, bb0, csr, offs, N, E, K);

    const int AGG_BLOCKS = (int)(((size_t)N * 8 + 255) / 256);

    // ---- 3 fused layers: agg (fp16 gather, fp32 accum) -> @W + b -> relu ----
    agg_fused_kernel<<<AGG_BLOCKS, 256, 0, stream>>>(xh, csr, offs, W1, b1, hA, N);
    agg_fused_kernel<<<AGG_BLOCKS, 256, 0, stream>>>(hA, csr, offs, W2, b2, hB, N);
    agg_fused_kernel<<<AGG_BLOCKS, 256, 0, stream>>>(hB, csr, offs, W3, b3, hA, N);

    // ---- pool + head ----
    pool_kernel<<<1024, 256, 0, stream>>>(hA, batch, sums, cnts, N);
    head_kernel<<<1, 256, 0, stream>>>(sums, cnts, lw1, lb1, lw2, lb2, lw3, lb3, out, G);
}